// Round 5
// baseline (284.343 us; speedup 1.0000x reference)
//
#include <hip/hip_runtime.h>
#include <hip/hip_bf16.h>
#include <stdint.h>

// Problem constants
#define OUT_DIM 4096
#define IN_DIM  4096
#define GROUPSZ 128
#define NGROUPS 32
#define M_TOTAL 8192   // 4 * 2048
#define EPS_Q   1e-12f

// GEMM tiling: 256x256 tile, BK=64, 8 waves (2M x 4N), m201 8-phase schedule
#define BM 256
#define BN 256
#define BK 64
#define NT (IN_DIM / BK)   // 64 K-tiles

typedef float f32x4   __attribute__((ext_vector_type(4)));
typedef float float4v __attribute__((ext_vector_type(4)));
typedef short bf16x8  __attribute__((ext_vector_type(8)));

static __device__ __forceinline__ short f2bf(float f) {
    union { float f; unsigned u; } v; v.f = f;
    unsigned r = v.u + 0x7fffu + ((v.u >> 16) & 1u);
    return (short)(r >> 16);
}

#define GLOAD16(gp, lp) __builtin_amdgcn_global_load_lds( \
    (const __attribute__((address_space(1))) void*)(gp),  \
    (__attribute__((address_space(3))) void*)(lp), 16, 0, 0)

// ---------------------------------------------------------------------------
// Kernel 1: dequantize W (bf16, [N][K] = B^T layout). One wave per (o, g).
// ---------------------------------------------------------------------------
__global__ __launch_bounds__(256) void dequant_kernel(
    const float* __restrict__ norms_p, const float* __restrict__ norms_r,
    const int* __restrict__ idx_p, const int* __restrict__ idx_r,
    short* __restrict__ W)
{
    const int gid  = (int)((blockIdx.x * 256u + threadIdx.x) >> 6);
    const int lane = threadIdx.x & 63;
    const size_t base = (size_t)gid * GROUPSZ;

    const int ip0 = idx_p[base + lane];
    const int ip1 = idx_p[base + lane + 64];
    const int ir0 = idx_r[base + lane];
    const int ir1 = idx_r[base + lane + 64];

    const float qp0 = -1.f + (2.f / 15.f) * (float)ip0;
    const float qp1 = -1.f + (2.f / 15.f) * (float)ip1;
    const float qr0 = -1.f + (2.f / 3.f)  * (float)ir0;
    const float qr1 = -1.f + (2.f / 3.f)  * (float)ir1;

    float ssp = qp0 * qp0 + qp1 * qp1;
    float ssr = qr0 * qr0 + qr1 * qr1;
    #pragma unroll
    for (int m = 32; m >= 1; m >>= 1) {
        ssp += __shfl_xor(ssp, m);
        ssr += __shfl_xor(ssr, m);
    }
    const float sp = norms_p[gid] / sqrtf(ssp + EPS_Q);
    const float sr = norms_r[gid] / sqrtf(ssr + EPS_Q);

    W[base + lane]      = f2bf(qp0 * sp + qr0 * sr);
    W[base + lane + 64] = f2bf(qp1 * sp + qr1 * sr);
}

// ---------------------------------------------------------------------------
// Kernel 2: x fp32 -> bf16, 8 elems/thread
// ---------------------------------------------------------------------------
__global__ __launch_bounds__(256) void cast_kernel(
    const float* __restrict__ x, short* __restrict__ xb)
{
    const size_t i = ((size_t)blockIdx.x * 256u + threadIdx.x) * 8u;
    float4v a = *(const float4v*)(x + i);
    float4v b = *(const float4v*)(x + i + 4);
    bf16x8 o;
    o[0] = f2bf(a[0]); o[1] = f2bf(a[1]); o[2] = f2bf(a[2]); o[3] = f2bf(a[3]);
    o[4] = f2bf(b[0]); o[5] = f2bf(b[1]); o[6] = f2bf(b[2]); o[7] = f2bf(b[3]);
    *(bf16x8*)(xb + i) = o;
}

// ---------------------------------------------------------------------------
// GEMM helpers (compile-time indexed everywhere — rule #20)
// ---------------------------------------------------------------------------
template<int HA, int HB>
__device__ __forceinline__ void mfma_quad(f32x4 (&acc)[2][2][4][2],
                                          const bf16x8 (&af)[4][2],
                                          const bf16x8 (&bf)[2][2]) {
#pragma unroll
    for (int m = 0; m < 4; ++m)
#pragma unroll
        for (int n = 0; n < 2; ++n)
#pragma unroll
            for (int kh = 0; kh < 2; ++kh)
                acc[HA][HB][m][n] = __builtin_amdgcn_mfma_f32_16x16x32_bf16(
                    af[m][kh], bf[n][kh], acc[HA][HB][m][n], 0, 0, 0);
}

static __device__ __forceinline__ void rd8(const short* base, int ck0, int ck1,
                                           bf16x8 (&f)[4][2]) {
#pragma unroll
    for (int m = 0; m < 4; ++m) {
        f[m][0] = *(const bf16x8*)(base + m * 1024 + ck0);
        f[m][1] = *(const bf16x8*)(base + m * 1024 + ck1);
    }
}

static __device__ __forceinline__ void rd4(const short* base, int ck0, int ck1,
                                           bf16x8 (&f)[2][2]) {
#pragma unroll
    for (int n = 0; n < 2; ++n) {
        f[n][0] = *(const bf16x8*)(base + n * 1024 + ck0);
        f[n][1] = *(const bf16x8*)(base + n * 1024 + ck1);
    }
}

#define BARRIER()  asm volatile("s_barrier" ::: "memory")
#define SCHEDBAR() __builtin_amdgcn_sched_barrier(0)
#define LGKMC(N)   do { asm volatile("s_waitcnt lgkmcnt(" #N ")" ::: "memory"); \
                        SCHEDBAR(); } while (0)
#define WAITV(N)   asm volatile("s_waitcnt vmcnt(" #N ")" ::: "memory")

// ---------------------------------------------------------------------------
// Kernel 3: C[M][N] = A[M][K] @ B[N][K]^T + bias, bf16 in / fp32 out.
// m201-faithful 8-phase schedule. Per K-tile (group), 4 phases; phase p:
//   { ds_read this phase's frags; stage exactly ONE half-tile (2 gload_lds);
//     [lgkmcnt(8) if 12 reads]; s_barrier; lgkmcnt(0); setprio(1);
//     16 MFMA (one C-quadrant); setprio(0); [vmcnt(6) if p3]; s_barrier }
// Quad order (0,0),(0,1),(1,1),(1,0); reads per phase 12/4/8/0.
// Stage per phase: p0: A1(t+1)->other buf; p1: A0(t+2)->this buf;
//                  p2: B0(t+2); p3: B1(t+2).
// Ledger (2 loads/half): steady-state vmcnt(6) at each group end leaves
// {A0,B0,B1}(t+2) in flight, guarantees tile t+1 fully landed.
// WAR hazards: each staged region's readers finished at their own lgkmcnt(0)
// before the end-of-phase barrier preceding the stage issue (checked/region).
// LDS 128 KiB: buf*32768 + {A0:0, A1:8192, B0:16384, B1:24576} shorts.
// Chunk swizzle: LDS chunk = global_chunk ^ (row&7) (both-sides involution).
// ---------------------------------------------------------------------------
__global__ __launch_bounds__(512, 2) void gemm_kernel(
    const short* __restrict__ Ag,  // [M][K] bf16
    const short* __restrict__ Bg,  // [N][K] bf16
    const float* __restrict__ bias,
    float* __restrict__ C)
{
    __shared__ short lds[65536];   // 128 KiB

    const int tid  = threadIdx.x;
    const int lane = tid & 63;
    const int wid  = tid >> 6;     // 0..7
    const int wr   = wid >> 2;     // 0..1 (M)
    const int wc   = wid & 3;      // 0..3 (N)
    const int fr   = lane & 15;
    const int lq   = lane >> 4;    // 0..3

    // bijective XCD swizzle (nwg = 512, divisible by 8)
    const int nwg = gridDim.x;
    const int cpx = nwg >> 3;
    const int wg  = ((int)blockIdx.x & 7) * cpx + ((int)blockIdx.x >> 3);
    const int ntile = wg & 15;              // N/BN = 16
    const int mtile = wg >> 4;              // M/BM = 32
    const uint32_t brow = (uint32_t)mtile * BM;
    const uint32_t bcol = (uint32_t)ntile * BN;

    // staging: slot s (0..1023): row r = s>>3, chunk c = s&7; thread owns
    // s = tid and s = tid+512. global chunk = c ^ (r&7).
    const uint32_t sr_ = (uint32_t)(tid >> 3);
    const uint32_t gc_ = (uint32_t)((tid & 7) ^ ((tid >> 3) & 7));
    const uint32_t aOffB = (brow + sr_) * IN_DIM + gc_ * 8;
    const uint32_t bOffB = (bcol + sr_) * IN_DIM + gc_ * 8;

    auto stage = [&](const short* M, uint32_t baseOff, uint32_t extra, short* dstRegion) {
        GLOAD16(M + baseOff + extra,            dstRegion + tid * 8);
        GLOAD16(M + baseOff + extra + 262144u,  dstRegion + tid * 8 + 4096);
    };

    // fragment read offsets (shorts): row*64 + ((kh*4+kc)^(fr&7))*8
    const int c0  = (lq ^ (fr & 7));
    const int ck0 = c0 * 8;
    const int ck1 = (c0 ^ 4) * 8;
    const int aRd = (wr * 64 + fr) * 64;
    const int bRd = (wc * 32 + fr) * 64;

    f32x4  acc[2][2][4][2] = {};
    bf16x8 af[4][2], af2[4][2], bf0[2][2], bf1[2][2];

    // prologue: 7 half-tiles in stream order (first 4 = all of tile 0)
    stage(Ag, aOffB, 0u,             lds);                    // A0(0)
    stage(Bg, bOffB, 0u,             lds + 16384);            // B0(0)
    stage(Bg, bOffB, 524288u,        lds + 24576);            // B1(0)
    stage(Ag, aOffB, 524288u,        lds + 8192);             // A1(0)
    stage(Ag, aOffB, 64u,            lds + 32768);            // A0(1)
    stage(Bg, bOffB, 64u,            lds + 32768 + 16384);    // B0(1)
    stage(Bg, bOffB, 524288u + 64u,  lds + 32768 + 24576);    // B1(1)
    WAITV(6);          // tile-0 halves landed; 3 halves outstanding
    BARRIER();

#define GROUP_BODY(SB, OB, TT, S_A1, S_A0, S_B0, S_B1, WAIT_END) do {         \
    /* phase 0: quad (0,0) — read A0(12 w/ B0), stage A1(T+1) */              \
    rd8((SB) + aRd, ck0, ck1, af);                                            \
    rd4((SB) + 16384 + bRd, ck0, ck1, bf0);                                   \
    if (S_A1) stage(Ag, aOffB, 524288u + (uint32_t)((TT)+1)*64u, (OB)+8192);  \
    LGKMC(8);                                                                 \
    BARRIER();                                                                \
    LGKMC(0);                                                                 \
    __builtin_amdgcn_s_setprio(1); mfma_quad<0,0>(acc, af, bf0);              \
    __builtin_amdgcn_s_setprio(0);                                            \
    BARRIER();                                                                \
    /* phase 1: quad (0,1) — read B1(4), stage A0(T+2) */                     \
    rd4((SB) + 24576 + bRd, ck0, ck1, bf1);                                   \
    if (S_A0) stage(Ag, aOffB, (uint32_t)((TT)+2)*64u, (SB));                 \
    BARRIER();                                                                \
    LGKMC(0);                                                                 \
    __builtin_amdgcn_s_setprio(1); mfma_quad<0,1>(acc, af, bf1);              \
    __builtin_amdgcn_s_setprio(0);                                            \
    BARRIER();                                                                \
    /* phase 2: quad (1,1) — read A1(8), stage B0(T+2) */                     \
    rd8((SB) + 8192 + aRd, ck0, ck1, af2);                                    \
    if (S_B0) stage(Bg, bOffB, (uint32_t)((TT)+2)*64u, (SB)+16384);           \
    BARRIER();                                                                \
    LGKMC(0);                                                                 \
    __builtin_amdgcn_s_setprio(1); mfma_quad<1,1>(acc, af2, bf1);             \
    __builtin_amdgcn_s_setprio(0);                                            \
    BARRIER();                                                                \
    /* phase 3: quad (1,0) — no reads, stage B1(T+2), vmcnt */                \
    if (S_B1) stage(Bg, bOffB, 524288u + (uint32_t)((TT)+2)*64u, (SB)+24576); \
    BARRIER();                                                                \
    SCHEDBAR();                                                               \
    __builtin_amdgcn_s_setprio(1); mfma_quad<1,0>(acc, af2, bf0);             \
    __builtin_amdgcn_s_setprio(0);                                            \
    WAIT_END;                                                                 \
    BARRIER();                                                                \
} while (0)

    #pragma unroll 1
    for (int t = 0; t < NT - 2; t += 2) {
        GROUP_BODY(lds,         lds + 32768, t,     1, 1, 1, 1, WAITV(6));
        GROUP_BODY(lds + 32768, lds,         t + 1, 1, 1, 1, 1, WAITV(6));
    }
    GROUP_BODY(lds,         lds + 32768, NT - 2, 1, 0, 0, 0, WAITV(0));
    GROUP_BODY(lds + 32768, lds,         NT - 1, 0, 0, 0, 0, (void)0);
#undef GROUP_BODY

    // epilogue: C/D layout col = lane&15, row = lq*4 + reg
    #pragma unroll
    for (int hA = 0; hA < 2; ++hA)
    #pragma unroll
    for (int hB = 0; hB < 2; ++hB)
    #pragma unroll
    for (int n = 0; n < 2; ++n) {
        const int col = (int)bcol + hB * 128 + wc * 32 + n * 16 + fr;
        const float bv = bias[col];
        #pragma unroll
        for (int m = 0; m < 4; ++m) {
            const size_t row0 = (size_t)brow + hA * 128 + wr * 64 + m * 16 + lq * 4;
            #pragma unroll
            for (int r = 0; r < 4; ++r)
                C[(row0 + r) * OUT_DIM + col] = acc[hA][hB][m][n][r] + bv;
        }
    }
}

// ---------------------------------------------------------------------------
extern "C" void kernel_launch(void* const* d_in, const int* in_sizes, int n_in,
                              void* d_out, int out_size, void* d_ws, size_t ws_size,
                              hipStream_t stream)
{
    const float* x        = (const float*)d_in[0];
    const float* norms_p  = (const float*)d_in[1];
    const float* norms_r  = (const float*)d_in[2];
    const float* bias     = (const float*)d_in[3];
    const int*   idx_p    = (const int*)d_in[4];
    const int*   idx_r    = (const int*)d_in[5];
    float*       out      = (float*)d_out;

    // workspace: xb (64 MB bf16 [M][K]) | W (32 MB bf16 [N][K])
    short* xb = (short*)d_ws;
    short* wq = (short*)d_ws + (size_t)M_TOTAL * IN_DIM;

    dequant_kernel<<<(OUT_DIM * NGROUPS) / 4, 256, 0, stream>>>(
        norms_p, norms_r, idx_p, idx_r, wq);

    cast_kernel<<<(int)(((size_t)M_TOTAL * IN_DIM) / (256 * 8)), 256, 0, stream>>>(x, xb);

    gemm_kernel<<<(M_TOTAL / BM) * (OUT_DIM / BN), 512, 0, stream>>>(xb, wq, bias, out);
}